// Round 9
// baseline (981.835 us; speedup 1.0000x reference)
//
#include <hip/hip_runtime.h>

// ---------------------------------------------------------------------------
// LSTM autoencoder: B=32, F=128, T=2400, H=256, SEG=24, S=100.
//  - outer encoder: FROZEN round-0 form (enc 270 us): depth-2 register ring,
//    per-step __syncthreads() drains -> blocks phase-locked on 786 KB W ->
//    ~99% L2 hit at the per-CU L2-return wall (~29-37 B/cy). DO NOT
//    restructure (rounds 1-5: any added register pressure spills -> 45-53 MB
//    scratch -> L2 thrash; rounds 6-7: global_load_lds DMA streams at only
//    ~16 B/cy).
//  - outer decoder / inner: raw barriers (no vmcnt drain of per-step global
//    stores) -- correctness-proven in round 1 (its regression was enc-only).
//  - inner decoder: t-invariant xw hoisted out of the 100-step loop.
//  - weight prep + input transpose fused into ONE launch.
// ---------------------------------------------------------------------------

#define B_    32
#define F_    128
#define T_    2400
#define H_    256
#define SEG_  24
#define S_    100
#define NSEQ_ 3200

using v2h = __attribute__((ext_vector_type(2))) _Float16;
using v4h = __attribute__((ext_vector_type(4))) _Float16;
using v8h = __attribute__((ext_vector_type(8))) _Float16;
using v4f = __attribute__((ext_vector_type(4))) float;

#ifndef __has_builtin
#define __has_builtin(x) 0
#endif

// Raw workgroup barrier (no counter drain). sched_barrier(0) on both sides
// pins scheduling (rule #18: asm "memory" clobber does not order MFMA/ds).
#define BARRIER_RAW()                                  \
  do {                                                 \
    __builtin_amdgcn_sched_barrier(0);                 \
    asm volatile("s_barrier" ::: "memory");            \
    __builtin_amdgcn_sched_barrier(0);                 \
  } while (0)

// Barrier draining LDS ops only (global stores stay in flight).
#define BARRIER_LGKM()                                              \
  do {                                                              \
    __builtin_amdgcn_sched_barrier(0);                              \
    asm volatile("s_waitcnt lgkmcnt(0)\n\ts_barrier" ::: "memory"); \
    __builtin_amdgcn_sched_barrier(0);                              \
  } while (0)

__device__ __forceinline__ float fdot2f(v2h a, v2h b, float c) {
#if __has_builtin(__builtin_amdgcn_fdot2)
  return __builtin_amdgcn_fdot2(a, b, c, false);
#else
  return c + (float)a[0] * (float)b[0] + (float)a[1] * (float)b[1];
#endif
}

// extract half2 pair e from a vector (constant-folds under #pragma unroll)
__device__ __forceinline__ v2h ext8(v8h v, int e) {
  v2h r; r[0] = v[2 * e]; r[1] = v[2 * e + 1]; return r;
}
__device__ __forceinline__ v2h ext4(v4h v, int e) {
  v2h r; r[0] = v[2 * e]; r[1] = v[2 * e + 1]; return r;
}

__device__ __forceinline__ float sigm(float x) { return 1.f / (1.f + __expf(-x)); }
__device__ __forceinline__ float tanh_f(float x) { return 1.f - 2.f / (__expf(2.f * x) + 1.f); }

// ---------------------------------------------------------------------------
// Fused weight prep + input transpose (one launch, 13152 x 256 threads):
//   [0,192)       wpack_oe  : [12][64][64] v8h fragment-major
//   [192,704)     wt2_ie    : transposed half2, G=1024, K=256
//   [704,1216)    wt2_id    : transposed half2, G=1024, K=256
//   [1216,1472)   wt2_od    : transposed half2, G=512,  K=256
//   [1472,1504)   wpack_od  : [4][32][64] v8h
//   [1504,2528)   whh_ie f16: 262144 elementwise casts
//   [2528,3552)   whh_id f16: 262144 elementwise casts
//   [3552,13152)  k_tin body: inp (B,F,T) fp32 -> xT[(b*2400+tau)][f] f16
// ---------------------------------------------------------------------------
__global__ __launch_bounds__(256) void k_prep(
    v8h* __restrict__ wpack_oe, v8h* __restrict__ wpack_od,
    v2h* __restrict__ wt2_ie, v2h* __restrict__ wt2_id, v2h* __restrict__ wt2_od,
    _Float16* __restrict__ whh_ie16, _Float16* __restrict__ whh_id16,
    const float* __restrict__ oe_wih, const float* __restrict__ oe_whh,
    const float* __restrict__ ie_wih, const float* __restrict__ ie_whh,
    const float* __restrict__ id_wih, const float* __restrict__ id_whh,
    const float* __restrict__ od_wih, const float* __restrict__ od_whh,
    const float* __restrict__ inp, _Float16* __restrict__ xT) {
  __shared__ float tile[32][33];
  const int tid = threadIdx.x;
  const int b = blockIdx.x;
  if (b < 192) {  // wpack_oe, 49152 items
    int idx = b * 256 + tid;
    int lane = idx & 63;
    int nt = (idx >> 6) & 63;
    int kc = idx >> 12;
    int col = nt * 16 + (lane & 15);
    int k0 = kc * 32 + (lane >> 4) * 8;
    v8h r;
#pragma unroll
    for (int j = 0; j < 8; ++j) {
      int k = k0 + j;
      float v = (k < 128) ? oe_wih[(size_t)col * 128 + k]
                          : oe_whh[(size_t)col * 256 + (k - 128)];
      r[j] = (_Float16)v;
    }
    wpack_oe[idx] = r;
  } else if (b < 704) {  // wt2_ie, n=131072, G=1024
    int idx = (b - 192) * 256 + tid;
    int k2 = idx >> 10, g = idx & 1023;
    int k = 2 * k2;
    v2h r;
    r[0] = (_Float16)ie_wih[(size_t)g * 256 + k];
    r[1] = (_Float16)ie_wih[(size_t)g * 256 + k + 1];
    wt2_ie[idx] = r;
  } else if (b < 1216) {  // wt2_id, n=131072, G=1024
    int idx = (b - 704) * 256 + tid;
    int k2 = idx >> 10, g = idx & 1023;
    int k = 2 * k2;
    v2h r;
    r[0] = (_Float16)id_wih[(size_t)g * 256 + k];
    r[1] = (_Float16)id_wih[(size_t)g * 256 + k + 1];
    wt2_id[idx] = r;
  } else if (b < 1472) {  // wt2_od, n=65536, G=512
    int idx = (b - 1216) * 256 + tid;
    int k2 = idx >> 9, g = idx & 511;
    int k = 2 * k2;
    v2h r;
    r[0] = (_Float16)od_wih[(size_t)g * 256 + k];
    r[1] = (_Float16)od_wih[(size_t)g * 256 + k + 1];
    wt2_od[idx] = r;
  } else if (b < 1504) {  // wpack_od, 8192 items
    int idx = (b - 1472) * 256 + tid;
    int lane = idx & 63;
    int nt = (idx >> 6) & 31;
    int kc = idx >> 11;
    int col = nt * 16 + (lane & 15);
    int k0 = kc * 32 + (lane >> 4) * 8;
    v8h r;
#pragma unroll
    for (int j = 0; j < 8; ++j) r[j] = (_Float16)od_whh[(size_t)col * 128 + k0 + j];
    wpack_od[idx] = r;
  } else if (b < 2528) {  // whh_ie -> f16
    int i = (b - 1504) * 256 + tid;
    whh_ie16[i] = (_Float16)ie_whh[i];
  } else if (b < 3552) {  // whh_id -> f16
    int i = (b - 2528) * 256 + tid;
    whh_id16[i] = (_Float16)id_whh[i];
  } else {  // input transpose
    int bi = b - 3552;                 // [0, 9600)
    int bx = bi % 75, by = (bi / 75) & 3, bz = bi / 300;
    int f0 = by * 32, t0 = bx * 32;
    int tx = tid & 31, ty = tid >> 5;  // (32, 8)
#pragma unroll
    for (int r = 0; r < 4; ++r) {
      int f = f0 + ty + 8 * r;
      tile[ty + 8 * r][tx] = inp[((size_t)bz * F_ + f) * T_ + t0 + tx];
    }
    __syncthreads();
#pragma unroll
    for (int r = 0; r < 4; ++r) {
      int tau = t0 + ty + 8 * r;
      xT[((size_t)bz * T_ + tau) * F_ + f0 + tx] = (_Float16)tile[tx][ty + 8 * r];
    }
  }
}

// Output transpose: rec[(b*2400+tau)][f] fp32 -> out (B,F,T) fp32
__global__ void k_tout(const float* __restrict__ rec, float* __restrict__ out) {
  __shared__ float tile[32][33];
  int b = blockIdx.z, f0 = blockIdx.y * 32, t0 = blockIdx.x * 32;
  int tx = threadIdx.x, ty = threadIdx.y;
#pragma unroll
  for (int r = 0; r < 4; ++r) {
    int tau = t0 + ty + 8 * r;
    tile[ty + 8 * r][tx] = rec[((size_t)b * T_ + tau) * F_ + f0 + tx];
  }
  __syncthreads();
#pragma unroll
  for (int r = 0; r < 4; ++r) {
    int f = f0 + ty + 8 * r;
    out[((size_t)b * F_ + f) * T_ + t0 + tx] = tile[tx][ty + 8 * r];
  }
}

// ---------------------------------------------------------------------------
// Outer encoder, MFMA version (round-0 exact -- FROZEN). Grid 100 x 512.
// Block: M=32 seqs. Wave w owns gate cols {g*256 + w*32 + jt*16 + c}.
// A=[x_t|h] in LDS (pitch 392 halves, conflict-free); W streamed from L2
// fragment-major, double-buffered; c-state in VGPRs.
// ---------------------------------------------------------------------------
__global__ __launch_bounds__(512, 2) void k_outer_enc_mfma(
    const v8h* __restrict__ wpack,    // [12][64][64] v8h
    const _Float16* __restrict__ xT,  // [(seq*24+t)*128 + f]
    const float* __restrict__ bih, const float* __restrict__ bhh,
    float* __restrict__ cst) {        // [3200][256] fp32
  __shared__ __align__(16) _Float16 a2[32][392];
  const int tid = threadIdx.x;
  const int w = tid >> 6;
  const int lane = tid & 63;
  const int cI = lane & 15;
  const int q = lane >> 4;
  const int seq0 = blockIdx.x * 32;

  float bias[4][2];
#pragma unroll
  for (int g = 0; g < 4; ++g)
#pragma unroll
    for (int jt = 0; jt < 2; ++jt) {
      int col = g * 256 + w * 32 + jt * 16 + cI;
      bias[g][jt] = bih[col] + bhh[col];
    }

  for (int i = tid; i < 32 * 256; i += 512) a2[i >> 8][128 + (i & 255)] = (_Float16)0.f;
  {
    int row = tid >> 4, ch = tid & 15;
    v8h xv = ((const v8h*)(xT + ((size_t)(seq0 + row) * SEG_ + 0) * F_))[ch];
    *(v8h*)(&a2[row][ch * 8]) = xv;
  }
  __syncthreads();

  float cs[2][2][4];
#pragma unroll
  for (int mt = 0; mt < 2; ++mt)
#pragma unroll
    for (int jt = 0; jt < 2; ++jt)
#pragma unroll
      for (int r = 0; r < 4; ++r) cs[mt][jt][r] = 0.f;

  for (int t = 0; t < SEG_; ++t) {
    v4f C[2][8];
#pragma unroll
    for (int mt = 0; mt < 2; ++mt)
#pragma unroll
      for (int n = 0; n < 8; ++n) {
        v4f z = {0.f, 0.f, 0.f, 0.f};
        C[mt][n] = z;
      }
    v8h Bf[2][8];
#pragma unroll
    for (int n = 0; n < 8; ++n) {
      int nt = (n >> 1) * 16 + w * 2 + (n & 1);
      Bf[0][n] = wpack[(size_t)(0 * 64 + nt) * 64 + lane];
    }
#pragma unroll 2
    for (int kc = 0; kc < 12; ++kc) {
      int cur = kc & 1, nxt = cur ^ 1;
      if (kc < 11) {
#pragma unroll
        for (int n = 0; n < 8; ++n) {
          int nt = (n >> 1) * 16 + w * 2 + (n & 1);
          Bf[nxt][n] = wpack[(size_t)((kc + 1) * 64 + nt) * 64 + lane];
        }
      }
      v8h A0 = *(const v8h*)(&a2[0 * 16 + cI][kc * 32 + q * 8]);
      v8h A1 = *(const v8h*)(&a2[1 * 16 + cI][kc * 32 + q * 8]);
#pragma unroll
      for (int n = 0; n < 8; ++n) {
        C[0][n] = __builtin_amdgcn_mfma_f32_16x16x32_f16(A0, Bf[cur][n], C[0][n], 0, 0, 0);
        C[1][n] = __builtin_amdgcn_mfma_f32_16x16x32_f16(A1, Bf[cur][n], C[1][n], 0, 0, 0);
      }
    }
    __syncthreads();
#pragma unroll
    for (int mt = 0; mt < 2; ++mt)
#pragma unroll
      for (int jt = 0; jt < 2; ++jt)
#pragma unroll
        for (int r = 0; r < 4; ++r) {
          float gi = sigm(C[mt][0 * 2 + jt][r] + bias[0][jt]);
          float gf = sigm(C[mt][1 * 2 + jt][r] + bias[1][jt]);
          float gg = tanh_f(C[mt][2 * 2 + jt][r] + bias[2][jt]);
          float go = sigm(C[mt][3 * 2 + jt][r] + bias[3][jt]);
          float cc = gf * cs[mt][jt][r] + gi * gg;
          cs[mt][jt][r] = cc;
          float h = go * tanh_f(cc);
          a2[mt * 16 + q * 4 + r][128 + w * 32 + jt * 16 + cI] = (_Float16)h;
        }
    if (t < SEG_ - 1) {
      int row = tid >> 4, ch = tid & 15;
      v8h xv = ((const v8h*)(xT + ((size_t)(seq0 + row) * SEG_ + (t + 1)) * F_))[ch];
      *(v8h*)(&a2[row][ch * 8]) = xv;
    }
    __syncthreads();
  }
#pragma unroll
  for (int mt = 0; mt < 2; ++mt)
#pragma unroll
    for (int jt = 0; jt < 2; ++jt)
#pragma unroll
      for (int r = 0; r < 4; ++r)
        cst[(size_t)(seq0 + mt * 16 + q * 4 + r) * H_ + w * 32 + jt * 16 + cI] = cs[mt][jt][r];
}

// ---------------------------------------------------------------------------
// Outer decoder, MFMA version. Grid 100 blocks x 512 threads (8 waves).
// Round-0 structure; barriers: #1 raw (A ds_reads already lgkm-consumed by
// MFMAs), #2 lgkm-only (ah write visible; rec stores stay in flight --
// __syncthreads was draining the store ack every step).
// ---------------------------------------------------------------------------
__global__ __launch_bounds__(512, 2) void k_outer_dec_mfma(
    const v8h* __restrict__ wpack,  // [4][32][64] v8h
    const float* __restrict__ xw,   // [3200][512] (biases folded)
    float* __restrict__ rec) {      // [3200*24][128] fp32
  __shared__ __align__(16) _Float16 ah[32][136];
  const int tid = threadIdx.x;
  const int w = tid >> 6;
  const int lane = tid & 63;
  const int cI = lane & 15;
  const int q = lane >> 4;
  const int seq0 = blockIdx.x * 32;

  v8h Bf[4][4];  // [kc][g]
#pragma unroll
  for (int kc = 0; kc < 4; ++kc)
#pragma unroll
    for (int g = 0; g < 4; ++g)
      Bf[kc][g] = wpack[(size_t)(kc * 32 + g * 8 + w) * 64 + lane];

  float xwr[2][4][4];
#pragma unroll
  for (int mt = 0; mt < 2; ++mt)
#pragma unroll
    for (int r = 0; r < 4; ++r) {
      int row = seq0 + mt * 16 + q * 4 + r;
#pragma unroll
      for (int g = 0; g < 4; ++g)
        xwr[mt][r][g] = xw[(size_t)row * 512 + g * 128 + w * 16 + cI];
    }

  for (int i = tid; i < 32 * 128; i += 512) ah[i >> 7][i & 127] = (_Float16)0.f;
  __syncthreads();

  float cs[2][4];
#pragma unroll
  for (int mt = 0; mt < 2; ++mt)
#pragma unroll
    for (int r = 0; r < 4; ++r) cs[mt][r] = 0.f;

#pragma unroll 1
  for (int t = 0; t < SEG_; ++t) {
    v4f C[2][4];
#pragma unroll
    for (int mt = 0; mt < 2; ++mt)
#pragma unroll
      for (int g = 0; g < 4; ++g) {
        v4f z = {0.f, 0.f, 0.f, 0.f};
        C[mt][g] = z;
      }
#pragma unroll
    for (int kc = 0; kc < 4; ++kc) {
      v8h A0 = *(const v8h*)(&ah[0 * 16 + cI][kc * 32 + q * 8]);
      v8h A1 = *(const v8h*)(&ah[1 * 16 + cI][kc * 32 + q * 8]);
#pragma unroll
      for (int g = 0; g < 4; ++g) {
        C[0][g] = __builtin_amdgcn_mfma_f32_16x16x32_f16(A0, Bf[kc][g], C[0][g], 0, 0, 0);
        C[1][g] = __builtin_amdgcn_mfma_f32_16x16x32_f16(A1, Bf[kc][g], C[1][g], 0, 0, 0);
      }
    }
    BARRIER_RAW();  // A reads done (consumed) before h rewrite; no vm drain
#pragma unroll
    for (int mt = 0; mt < 2; ++mt)
#pragma unroll
      for (int r = 0; r < 4; ++r) {
        float gi = sigm(C[mt][0][r] + xwr[mt][r][0]);
        float gf = sigm(C[mt][1][r] + xwr[mt][r][1]);
        float gg = tanh_f(C[mt][2][r] + xwr[mt][r][2]);
        float go = sigm(C[mt][3][r] + xwr[mt][r][3]);
        float cc = gf * cs[mt][r] + gi * gg;
        cs[mt][r] = cc;
        float h = go * tanh_f(cc);
        int row = mt * 16 + q * 4 + r;
        ah[row][w * 16 + cI] = (_Float16)h;
        rec[((size_t)(seq0 + row) * SEG_ + t) * 128 + w * 16 + cI] = h;
      }
    BARRIER_LGKM();  // drain LDS h writes only; rec stores stay in flight
  }
}

// ---------------------------------------------------------------------------
// Batched input projection: out[M][G] = A[M][256] @ wt2[128][G] + b1 + b2.
// ---------------------------------------------------------------------------
template <int GT>
__global__ __launch_bounds__(256) void k_proj(
    const float* __restrict__ A, const v2h* __restrict__ wt2,
    const float* __restrict__ b1, const float* __restrict__ b2,
    float* __restrict__ out) {
  constexpr int G = GT * 256;
  __shared__ __align__(16) _Float16 a2[16][256];
  const int tid = threadIdx.x;
  const size_t row0 = (size_t)blockIdx.x * 16;
  for (int idx = tid; idx < 16 * 256; idx += 256) {
    int r = idx >> 8, k = idx & 255;
    a2[r][k] = (_Float16)A[(row0 + (size_t)r) * 256 + k];
  }
  __syncthreads();
  float acc[16][GT];
#pragma unroll
  for (int r = 0; r < 16; ++r)
#pragma unroll
    for (int q = 0; q < GT; ++q) acc[r][q] = 0.f;
  const v2h* wp = wt2 + tid;
#pragma unroll 2
  for (int k2 = 0; k2 < 128; ++k2) {
    v2h w[GT];
#pragma unroll
    for (int q = 0; q < GT; ++q) w[q] = wp[256 * q];
    wp += G;
#pragma unroll
    for (int r = 0; r < 16; ++r) {
      v2h a = ((const v2h*)&a2[r][0])[k2];
#pragma unroll
      for (int q = 0; q < GT; ++q) acc[r][q] = fdot2f(w[q], a, acc[r][q]);
    }
  }
#pragma unroll
  for (int q = 0; q < GT; ++q) {
    float bias = b1[tid + 256 * q] + b2[tid + 256 * q];
#pragma unroll
    for (int r = 0; r < 16; ++r)
      out[(row0 + (size_t)r) * G + tid + 256 * q] = acc[r][q] + bias;
  }
}

// ---------------------------------------------------------------------------
// Inner LSTM (encoder/decoder): 1 block per batch element, 512 threads.
// Barriers: #1 raw (each wave's ah ds_reads are consumed before arrival),
// #2 lgkm-only (ah write visible; h_out stores stay in flight -- the old
// __syncthreads drained the store ack on every one of 100 steps).
// xw hoisted out of the t-loop when xw_t_stride==0 (inner decoder).
// ---------------------------------------------------------------------------
__global__ __launch_bounds__(512) void k_inner(
    const _Float16* __restrict__ whh,  // [1024][256] row-major f16
    const float* __restrict__ xw, long xw_seq_stride, long xw_t_stride, int T,
    float* __restrict__ h_out,   // [B*T][256] or nullptr
    float* __restrict__ c_out) { // [B][256] or nullptr
  __shared__ __align__(16) _Float16 ah[H_];
  __shared__ __align__(16) _Float16 wo[H_][260];
  const int t_ = threadIdx.x;
  const int p = t_ >> 1;
  const int hf = t_ & 1;
  const int b = blockIdx.x;

  v8h wv[3][16];
#pragma unroll
  for (int r = 0; r < 3; ++r) {
    const v8h* src = (const v8h*)(whh + ((size_t)(H_ * r + p)) * H_ + hf * 128);
#pragma unroll
    for (int q = 0; q < 16; ++q) wv[r][q] = src[q];
  }
  {
    const v4h* src = (const v4h*)(whh + ((size_t)(H_ * 3 + p)) * H_ + hf * 128);
    v4h* dst = (v4h*)&wo[p][hf * 128];
#pragma unroll
    for (int q = 0; q < 32; ++q) dst[q] = src[q];
  }
  if (t_ < H_) ah[t_] = (_Float16)0.f;
  float c = 0.f;

  // hoist t-invariant xw (inner decoder: xw_t_stride == 0)
  const bool xconst = (xw_t_stride == 0);
  float xc0 = 0.f, xc1 = 0.f, xc2 = 0.f, xc3 = 0.f;
  if (xconst) {
    const float* xwp = xw + (size_t)b * xw_seq_stride;
    xc0 = xwp[p]; xc1 = xwp[H_ + p]; xc2 = xwp[2 * H_ + p]; xc3 = xwp[3 * H_ + p];
  }
  __syncthreads();

#pragma unroll 1
  for (int t = 0; t < T; ++t) {
    float x0, x1, x2, x3;
    if (xconst) {
      x0 = xc0; x1 = xc1; x2 = xc2; x3 = xc3;
    } else {
      const float* xwp = xw + (size_t)b * xw_seq_stride + (size_t)t * xw_t_stride;
      x0 = xwp[p]; x1 = xwp[H_ + p]; x2 = xwp[2 * H_ + p]; x3 = xwp[3 * H_ + p];
    }
    float a0 = 0.f, a1 = 0.f, a2 = 0.f, a3 = 0.f;
    const v8h* A8 = ((const v8h*)ah) + hf * 16;
    const v4h* O4 = (const v4h*)&wo[p][hf * 128];
#pragma unroll
    for (int q = 0; q < 16; ++q) {
      v8h av = A8[q];
      v8h w0v = wv[0][q], w1v = wv[1][q], w2v = wv[2][q];
      v4h o0 = O4[2 * q], o1 = O4[2 * q + 1];
#pragma unroll
      for (int e = 0; e < 4; ++e) {
        v2h ap = ext8(av, e);
        a0 = fdot2f(ext8(w0v, e), ap, a0);
        a1 = fdot2f(ext8(w1v, e), ap, a1);
        a2 = fdot2f(ext8(w2v, e), ap, a2);
        v2h op = (e < 2) ? ext4(o0, e) : ext4(o1, e - 2);
        a3 = fdot2f(op, ap, a3);
      }
    }
    a0 += __shfl_xor(a0, 1);
    a1 += __shfl_xor(a1, 1);
    a2 += __shfl_xor(a2, 1);
    a3 += __shfl_xor(a3, 1);
    float gi = sigm(a0 + x0);
    float gf = sigm(a1 + x1);
    float gg = tanh_f(a2 + x2);
    float go = sigm(a3 + x3);
    c = gf * c + gi * gg;
    float h = go * tanh_f(c);
    BARRIER_RAW();  // all ah reads consumed; no counter drain
    if (hf == 0) {
      ah[p] = (_Float16)h;
      if (h_out) h_out[((size_t)b * T + t) * H_ + p] = h;
    }
    BARRIER_LGKM();  // drain ah write; h_out store stays in flight
  }
  if (c_out && hf == 0) c_out[(size_t)b * H_ + p] = c;
}

// ---------------------------------------------------------------------------
extern "C" void kernel_launch(void* const* d_in, const int* in_sizes, int n_in,
                              void* d_out, int out_size, void* d_ws, size_t ws_size,
                              hipStream_t stream) {
  const float* inp    = (const float*)d_in[0];
  const float* oe_wih = (const float*)d_in[1];
  const float* oe_whh = (const float*)d_in[2];
  const float* oe_bih = (const float*)d_in[3];
  const float* oe_bhh = (const float*)d_in[4];
  const float* ie_wih = (const float*)d_in[5];
  const float* ie_whh = (const float*)d_in[6];
  const float* ie_bih = (const float*)d_in[7];
  const float* ie_bhh = (const float*)d_in[8];
  const float* id_wih = (const float*)d_in[9];
  const float* id_whh = (const float*)d_in[10];
  const float* id_bih = (const float*)d_in[11];
  const float* id_bhh = (const float*)d_in[12];
  const float* od_wih = (const float*)d_in[13];
  const float* od_whh = (const float*)d_in[14];
  const float* od_bih = (const float*)d_in[15];
  const float* od_bhh = (const float*)d_in[16];

  char* ws = (char*)d_ws;
  _Float16* xT     = (_Float16*)(ws + 0);         // 76800*128 f16 = 19,660,800
  v8h* wpack_oe    = (v8h*)(ws + 19660800);       // 12*64*64*16  =    786,432
  float* cst       = (float*)(ws + 20447232);     // 3200*256*4   =  3,276,800
  v2h* wt2_ie      = (v2h*)(ws + 23724032);       // 128*1024*4   =    524,288
  float* xw_ie     = (float*)(ws + 24248320);     // 3200*1024*4  = 13,107,200
  _Float16* whh_ie = (_Float16*)(ws + 37355520);  // 262144 f16   =    524,288
  float* bott      = (float*)(ws + 37879808);     // 32*256*4     =     32,768
  v2h* wt2_id      = (v2h*)(ws + 37912576);       //              =    524,288
  float* xw_id     = (float*)(ws + 38436864);     // 32*1024*4    =    131,072
  _Float16* whh_id = (_Float16*)(ws + 38567936);  //              =    524,288
  float* dec       = (float*)(ws + 39092224);     // 3200*256*4   =  3,276,800
  v2h* wt2_odih    = (v2h*)(ws + 42369024);       // 128*512*4    =    262,144
  float* xw_od     = (float*)(ws + 42631168);     // 3200*512*4   =  6,553,600
  v8h* wpack_od    = (v8h*)(ws + 49184768);       // 4*32*64*16   =    131,072
  float* rec       = (float*)(ws + 49315840);     // 76800*128*4  = 39,321,600  (end 88.6 MB)

  // --- weight prep + input transpose (fused: one launch) ---
  k_prep<<<dim3(13152), dim3(256), 0, stream>>>(
      wpack_oe, wpack_od, wt2_ie, wt2_id, wt2_odih, whh_ie, whh_id,
      oe_wih, oe_whh, ie_wih, ie_whh, id_wih, id_whh, od_wih, od_whh,
      inp, xT);

  // --- pipeline ---
  k_outer_enc_mfma<<<dim3(100), dim3(512), 0, stream>>>(wpack_oe, xT, oe_bih, oe_bhh, cst);
  k_proj<4><<<dim3(200), dim3(256), 0, stream>>>(cst, wt2_ie, ie_bih, ie_bhh, xw_ie);
  k_inner<<<dim3(32), dim3(512), 0, stream>>>(whh_ie, xw_ie, (long)S_ * 1024, 1024, S_, nullptr, bott);
  k_proj<4><<<dim3(2), dim3(256), 0, stream>>>(bott, wt2_id, id_bih, id_bhh, xw_id);
  k_inner<<<dim3(32), dim3(512), 0, stream>>>(whh_id, xw_id, 1024, 0, S_, dec, nullptr);
  k_proj<2><<<dim3(200), dim3(256), 0, stream>>>(dec, wt2_odih, od_bih, od_bhh, xw_od);
  k_outer_dec_mfma<<<dim3(100), dim3(512), 0, stream>>>(wpack_od, xw_od, rec);
  k_tout<<<dim3(75, 4, 32), dim3(32, 8), 0, stream>>>(rec, (float*)d_out);

  (void)in_sizes; (void)n_in; (void)out_size; (void)ws_size;
}

// Round 10
// 971.441 us; speedup vs baseline: 1.0107x; 1.0107x over previous
//
#include <hip/hip_runtime.h>

// ---------------------------------------------------------------------------
// LSTM autoencoder: B=32, F=128, T=2400, H=256, SEG=24, S=100.
//  - outer encoder: FROZEN round-0 form (enc 270 us): depth-2 register ring,
//    per-step __syncthreads() drains -> blocks phase-locked on 786 KB W ->
//    ~99% L2 hit at the per-CU L2-return wall (~29-37 B/cy). DO NOT
//    restructure (rounds 1-5: any added register pressure spills -> 45-53 MB
//    scratch -> L2 thrash; rounds 6-7: global_load_lds DMA streams at only
//    ~16 B/cy).
//  - outer decoder: M-SPLIT across waves (1024 thr, 16 waves; wave owns one
//    mt half). Per-thread regs ~116 <= the 128 cap -- the old 8-wave form
//    needed ~156 and was very likely silently spill-reloading ~28 regs/thread
//    every step (invisible: dec < enc's 270 us top-5 saturation).
//  - inner encoder/decoder + proj + prep: round-8 exact (measured best).
// ---------------------------------------------------------------------------

#define B_    32
#define F_    128
#define T_    2400
#define H_    256
#define SEG_  24
#define S_    100
#define NSEQ_ 3200

using v2h = __attribute__((ext_vector_type(2))) _Float16;
using v4h = __attribute__((ext_vector_type(4))) _Float16;
using v8h = __attribute__((ext_vector_type(8))) _Float16;
using v4f = __attribute__((ext_vector_type(4))) float;

#ifndef __has_builtin
#define __has_builtin(x) 0
#endif

__device__ __forceinline__ float fdot2f(v2h a, v2h b, float c) {
#if __has_builtin(__builtin_amdgcn_fdot2)
  return __builtin_amdgcn_fdot2(a, b, c, false);
#else
  return c + (float)a[0] * (float)b[0] + (float)a[1] * (float)b[1];
#endif
}

// extract half2 pair e from a vector (constant-folds under #pragma unroll)
__device__ __forceinline__ v2h ext8(v8h v, int e) {
  v2h r; r[0] = v[2 * e]; r[1] = v[2 * e + 1]; return r;
}
__device__ __forceinline__ v2h ext4(v4h v, int e) {
  v2h r; r[0] = v[2 * e]; r[1] = v[2 * e + 1]; return r;
}

__device__ __forceinline__ float sigm(float x) { return 1.f / (1.f + __expf(-x)); }
__device__ __forceinline__ float tanh_f(float x) { return 1.f - 2.f / (__expf(2.f * x) + 1.f); }

// ---------------------------------------------------------------------------
// Fused weight prep (one launch, grid 3552 x 256, branch by block range):
//   [0,192)     wpack_oe  : [12][64][64] v8h fragment-major (round-0 layout)
//   [192,704)   wt2_ie    : transposed half2, G=1024, K=256
//   [704,1216)  wt2_id    : transposed half2, G=1024, K=256
//   [1216,1472) wt2_od    : transposed half2, G=512,  K=256
//   [1472,1504) wpack_od  : [4][32][64] v8h
//   [1504,2528) whh_ie f16: 262144 elementwise casts
//   [2528,3552) whh_id f16: 262144 elementwise casts
// ---------------------------------------------------------------------------
__global__ __launch_bounds__(256) void k_prep(
    v8h* __restrict__ wpack_oe, v8h* __restrict__ wpack_od,
    v2h* __restrict__ wt2_ie, v2h* __restrict__ wt2_id, v2h* __restrict__ wt2_od,
    _Float16* __restrict__ whh_ie16, _Float16* __restrict__ whh_id16,
    const float* __restrict__ oe_wih, const float* __restrict__ oe_whh,
    const float* __restrict__ ie_wih, const float* __restrict__ ie_whh,
    const float* __restrict__ id_wih, const float* __restrict__ id_whh,
    const float* __restrict__ od_wih, const float* __restrict__ od_whh) {
  const int tid = threadIdx.x;
  const int b = blockIdx.x;
  if (b < 192) {  // wpack_oe, 49152 items
    int idx = b * 256 + tid;
    int lane = idx & 63;
    int nt = (idx >> 6) & 63;
    int kc = idx >> 12;
    int col = nt * 16 + (lane & 15);
    int k0 = kc * 32 + (lane >> 4) * 8;
    v8h r;
#pragma unroll
    for (int j = 0; j < 8; ++j) {
      int k = k0 + j;
      float v = (k < 128) ? oe_wih[(size_t)col * 128 + k]
                          : oe_whh[(size_t)col * 256 + (k - 128)];
      r[j] = (_Float16)v;
    }
    wpack_oe[idx] = r;
  } else if (b < 704) {  // wt2_ie, n=131072, G=1024
    int idx = (b - 192) * 256 + tid;
    int k2 = idx >> 10, g = idx & 1023;
    int k = 2 * k2;
    v2h r;
    r[0] = (_Float16)ie_wih[(size_t)g * 256 + k];
    r[1] = (_Float16)ie_wih[(size_t)g * 256 + k + 1];
    wt2_ie[idx] = r;
  } else if (b < 1216) {  // wt2_id, n=131072, G=1024
    int idx = (b - 704) * 256 + tid;
    int k2 = idx >> 10, g = idx & 1023;
    int k = 2 * k2;
    v2h r;
    r[0] = (_Float16)id_wih[(size_t)g * 256 + k];
    r[1] = (_Float16)id_wih[(size_t)g * 256 + k + 1];
    wt2_id[idx] = r;
  } else if (b < 1472) {  // wt2_od, n=65536, G=512
    int idx = (b - 1216) * 256 + tid;
    int k2 = idx >> 9, g = idx & 511;
    int k = 2 * k2;
    v2h r;
    r[0] = (_Float16)od_wih[(size_t)g * 256 + k];
    r[1] = (_Float16)od_wih[(size_t)g * 256 + k + 1];
    wt2_od[idx] = r;
  } else if (b < 1504) {  // wpack_od, 8192 items
    int idx = (b - 1472) * 256 + tid;
    int lane = idx & 63;
    int nt = (idx >> 6) & 31;
    int kc = idx >> 11;
    int col = nt * 16 + (lane & 15);
    int k0 = kc * 32 + (lane >> 4) * 8;
    v8h r;
#pragma unroll
    for (int j = 0; j < 8; ++j) r[j] = (_Float16)od_whh[(size_t)col * 128 + k0 + j];
    wpack_od[idx] = r;
  } else if (b < 2528) {  // whh_ie -> f16
    int i = (b - 1504) * 256 + tid;
    whh_ie16[i] = (_Float16)ie_whh[i];
  } else {  // whh_id -> f16
    int i = (b - 2528) * 256 + tid;
    whh_id16[i] = (_Float16)id_whh[i];
  }
}

// ---------------------------------------------------------------------------
// Input transpose: inp (B,F,T) fp32 -> xT[(b*2400+tau)][f] f16  (tau = s*24+t)
// ---------------------------------------------------------------------------
__global__ void k_tin(const float* __restrict__ inp, _Float16* __restrict__ xT) {
  __shared__ float tile[32][33];
  int b = blockIdx.z, f0 = blockIdx.y * 32, t0 = blockIdx.x * 32;
  int tx = threadIdx.x, ty = threadIdx.y;
#pragma unroll
  for (int r = 0; r < 4; ++r) {
    int f = f0 + ty + 8 * r;
    tile[ty + 8 * r][tx] = inp[((size_t)b * F_ + f) * T_ + t0 + tx];
  }
  __syncthreads();
#pragma unroll
  for (int r = 0; r < 4; ++r) {
    int tau = t0 + ty + 8 * r;
    xT[((size_t)b * T_ + tau) * F_ + f0 + tx] = (_Float16)tile[tx][ty + 8 * r];
  }
}

// Output transpose: rec[(b*2400+tau)][f] fp32 -> out (B,F,T) fp32
__global__ void k_tout(const float* __restrict__ rec, float* __restrict__ out) {
  __shared__ float tile[32][33];
  int b = blockIdx.z, f0 = blockIdx.y * 32, t0 = blockIdx.x * 32;
  int tx = threadIdx.x, ty = threadIdx.y;
#pragma unroll
  for (int r = 0; r < 4; ++r) {
    int tau = t0 + ty + 8 * r;
    tile[ty + 8 * r][tx] = rec[((size_t)b * T_ + tau) * F_ + f0 + tx];
  }
  __syncthreads();
#pragma unroll
  for (int r = 0; r < 4; ++r) {
    int f = f0 + ty + 8 * r;
    out[((size_t)b * F_ + f) * T_ + t0 + tx] = tile[tx][ty + 8 * r];
  }
}

// ---------------------------------------------------------------------------
// Outer encoder, MFMA version (round-0 exact -- FROZEN). Grid 100 x 512.
// Block: M=32 seqs. Wave w owns gate cols {g*256 + w*32 + jt*16 + c}.
// A=[x_t|h] in LDS (pitch 392 halves, conflict-free); W streamed from L2
// fragment-major, double-buffered; c-state in VGPRs.
// ---------------------------------------------------------------------------
__global__ __launch_bounds__(512, 2) void k_outer_enc_mfma(
    const v8h* __restrict__ wpack,    // [12][64][64] v8h
    const _Float16* __restrict__ xT,  // [(seq*24+t)*128 + f]
    const float* __restrict__ bih, const float* __restrict__ bhh,
    float* __restrict__ cst) {        // [3200][256] fp32
  __shared__ __align__(16) _Float16 a2[32][392];
  const int tid = threadIdx.x;
  const int w = tid >> 6;
  const int lane = tid & 63;
  const int cI = lane & 15;
  const int q = lane >> 4;
  const int seq0 = blockIdx.x * 32;

  float bias[4][2];
#pragma unroll
  for (int g = 0; g < 4; ++g)
#pragma unroll
    for (int jt = 0; jt < 2; ++jt) {
      int col = g * 256 + w * 32 + jt * 16 + cI;
      bias[g][jt] = bih[col] + bhh[col];
    }

  for (int i = tid; i < 32 * 256; i += 512) a2[i >> 8][128 + (i & 255)] = (_Float16)0.f;
  {
    int row = tid >> 4, ch = tid & 15;
    v8h xv = ((const v8h*)(xT + ((size_t)(seq0 + row) * SEG_ + 0) * F_))[ch];
    *(v8h*)(&a2[row][ch * 8]) = xv;
  }
  __syncthreads();

  float cs[2][2][4];
#pragma unroll
  for (int mt = 0; mt < 2; ++mt)
#pragma unroll
    for (int jt = 0; jt < 2; ++jt)
#pragma unroll
      for (int r = 0; r < 4; ++r) cs[mt][jt][r] = 0.f;

  for (int t = 0; t < SEG_; ++t) {
    v4f C[2][8];
#pragma unroll
    for (int mt = 0; mt < 2; ++mt)
#pragma unroll
      for (int n = 0; n < 8; ++n) {
        v4f z = {0.f, 0.f, 0.f, 0.f};
        C[mt][n] = z;
      }
    v8h Bf[2][8];
#pragma unroll
    for (int n = 0; n < 8; ++n) {
      int nt = (n >> 1) * 16 + w * 2 + (n & 1);
      Bf[0][n] = wpack[(size_t)(0 * 64 + nt) * 64 + lane];
    }
#pragma unroll 2
    for (int kc = 0; kc < 12; ++kc) {
      int cur = kc & 1, nxt = cur ^ 1;
      if (kc < 11) {
#pragma unroll
        for (int n = 0; n < 8; ++n) {
          int nt = (n >> 1) * 16 + w * 2 + (n & 1);
          Bf[nxt][n] = wpack[(size_t)((kc + 1) * 64 + nt) * 64 + lane];
        }
      }
      v8h A0 = *(const v8h*)(&a2[0 * 16 + cI][kc * 32 + q * 8]);
      v8h A1 = *(const v8h*)(&a2[1 * 16 + cI][kc * 32 + q * 8]);
#pragma unroll
      for (int n = 0; n < 8; ++n) {
        C[0][n] = __builtin_amdgcn_mfma_f32_16x16x32_f16(A0, Bf[cur][n], C[0][n], 0, 0, 0);
        C[1][n] = __builtin_amdgcn_mfma_f32_16x16x32_f16(A1, Bf[cur][n], C[1][n], 0, 0, 0);
      }
    }
    __syncthreads();
#pragma unroll
    for (int mt = 0; mt < 2; ++mt)
#pragma unroll
      for (int jt = 0; jt < 2; ++jt)
#pragma unroll
        for (int r = 0; r < 4; ++r) {
          float gi = sigm(C[mt][0 * 2 + jt][r] + bias[0][jt]);
          float gf = sigm(C[mt][1 * 2 + jt][r] + bias[1][jt]);
          float gg = tanh_f(C[mt][2 * 2 + jt][r] + bias[2][jt]);
          float go = sigm(C[mt][3 * 2 + jt][r] + bias[3][jt]);
          float cc = gf * cs[mt][jt][r] + gi * gg;
          cs[mt][jt][r] = cc;
          float h = go * tanh_f(cc);
          a2[mt * 16 + q * 4 + r][128 + w * 32 + jt * 16 + cI] = (_Float16)h;
        }
    if (t < SEG_ - 1) {
      int row = tid >> 4, ch = tid & 15;
      v8h xv = ((const v8h*)(xT + ((size_t)(seq0 + row) * SEG_ + (t + 1)) * F_))[ch];
      *(v8h*)(&a2[row][ch * 8]) = xv;
    }
    __syncthreads();
  }
#pragma unroll
  for (int mt = 0; mt < 2; ++mt)
#pragma unroll
    for (int jt = 0; jt < 2; ++jt)
#pragma unroll
      for (int r = 0; r < 4; ++r)
        cst[(size_t)(seq0 + mt * 16 + q * 4 + r) * H_ + w * 32 + jt * 16 + cI] = cs[mt][jt][r];
}

// ---------------------------------------------------------------------------
// Outer decoder, MFMA, M-split. Grid 100 blocks x 1024 threads (16 waves).
// Wave w5: mt = w5>>3 (row half), w = w5&7 (gate-col slice, as before).
// Per-thread regs: Bf[4][4]=64 + xwr[4][4]=16 + C[4]=16 + cs[4]=4 + ~16 misc
// = ~116 <= the 128-VGPR cap at 4 waves/SIMD -- the old 8-wave form needed
// ~156 (Bf 64 + xwr 32 + C 32 + cs 8 + misc) and silently spill-reloaded
// every step. Same 256 MFMA/step/block, same LDS, same math.
// ---------------------------------------------------------------------------
__global__ __launch_bounds__(1024, 1) void k_outer_dec_mfma(
    const v8h* __restrict__ wpack,  // [4][32][64] v8h
    const float* __restrict__ xw,   // [3200][512] (biases folded)
    float* __restrict__ rec) {      // [3200*24][128] fp32
  __shared__ __align__(16) _Float16 ah[32][136];
  const int tid = threadIdx.x;
  const int w5 = tid >> 6;   // 0..15
  const int mt = w5 >> 3;    // 0..1 : M half owned by this wave
  const int w  = w5 & 7;     // 0..7 : gate-col slice (as in 8-wave form)
  const int lane = tid & 63;
  const int cI = lane & 15;
  const int q = lane >> 4;
  const int seq0 = blockIdx.x * 32;

  v8h Bf[4][4];  // [kc][g]
#pragma unroll
  for (int kc = 0; kc < 4; ++kc)
#pragma unroll
    for (int g = 0; g < 4; ++g)
      Bf[kc][g] = wpack[(size_t)(kc * 32 + g * 8 + w) * 64 + lane];

  float xwr[4][4];  // [r][g], t-invariant
#pragma unroll
  for (int r = 0; r < 4; ++r) {
    int row = seq0 + mt * 16 + q * 4 + r;
#pragma unroll
    for (int g = 0; g < 4; ++g)
      xwr[r][g] = xw[(size_t)row * 512 + g * 128 + w * 16 + cI];
  }

  for (int i = tid; i < 32 * 128; i += 1024) ah[i >> 7][i & 127] = (_Float16)0.f;
  __syncthreads();

  float cs[4];
#pragma unroll
  for (int r = 0; r < 4; ++r) cs[r] = 0.f;

  for (int t = 0; t < SEG_; ++t) {
    v4f C[4];
#pragma unroll
    for (int g = 0; g < 4; ++g) {
      v4f z = {0.f, 0.f, 0.f, 0.f};
      C[g] = z;
    }
#pragma unroll
    for (int kc = 0; kc < 4; ++kc) {
      v8h A0 = *(const v8h*)(&ah[mt * 16 + cI][kc * 32 + q * 8]);
#pragma unroll
      for (int g = 0; g < 4; ++g)
        C[g] = __builtin_amdgcn_mfma_f32_16x16x32_f16(A0, Bf[kc][g], C[g], 0, 0, 0);
    }
    __syncthreads();  // A reads done before h rewrite
#pragma unroll
    for (int r = 0; r < 4; ++r) {
      float gi = sigm(C[0][r] + xwr[r][0]);
      float gf = sigm(C[1][r] + xwr[r][1]);
      float gg = tanh_f(C[2][r] + xwr[r][2]);
      float go = sigm(C[3][r] + xwr[r][3]);
      float cc = gf * cs[r] + gi * gg;
      cs[r] = cc;
      float h = go * tanh_f(cc);
      int row = mt * 16 + q * 4 + r;
      ah[row][w * 16 + cI] = (_Float16)h;
      rec[((size_t)(seq0 + row) * SEG_ + t) * 128 + w * 16 + cI] = h;
    }
    __syncthreads();
  }
}

// ---------------------------------------------------------------------------
// Batched input projection: out[M][G] = A[M][256] @ wt2[128][G] + b1 + b2.
// ---------------------------------------------------------------------------
template <int GT>
__global__ __launch_bounds__(256) void k_proj(
    const float* __restrict__ A, const v2h* __restrict__ wt2,
    const float* __restrict__ b1, const float* __restrict__ b2,
    float* __restrict__ out) {
  constexpr int G = GT * 256;
  __shared__ __align__(16) _Float16 a2[16][256];
  const int tid = threadIdx.x;
  const size_t row0 = (size_t)blockIdx.x * 16;
  for (int idx = tid; idx < 16 * 256; idx += 256) {
    int r = idx >> 8, k = idx & 255;
    a2[r][k] = (_Float16)A[(row0 + (size_t)r) * 256 + k];
  }
  __syncthreads();
  float acc[16][GT];
#pragma unroll
  for (int r = 0; r < 16; ++r)
#pragma unroll
    for (int q = 0; q < GT; ++q) acc[r][q] = 0.f;
  const v2h* wp = wt2 + tid;
#pragma unroll 2
  for (int k2 = 0; k2 < 128; ++k2) {
    v2h w[GT];
#pragma unroll
    for (int q = 0; q < GT; ++q) w[q] = wp[256 * q];
    wp += G;
#pragma unroll
    for (int r = 0; r < 16; ++r) {
      v2h a = ((const v2h*)&a2[r][0])[k2];
#pragma unroll
      for (int q = 0; q < GT; ++q) acc[r][q] = fdot2f(w[q], a, acc[r][q]);
    }
  }
#pragma unroll
  for (int q = 0; q < GT; ++q) {
    float bias = b1[tid + 256 * q] + b2[tid + 256 * q];
#pragma unroll
    for (int r = 0; r < 16; ++r)
      out[(row0 + (size_t)r) * G + tid + 256 * q] = acc[r][q] + bias;
  }
}

// ---------------------------------------------------------------------------
// Inner LSTM (encoder/decoder): 1 block per batch element, 512 threads.
// ---------------------------------------------------------------------------
__global__ __launch_bounds__(512) void k_inner(
    const _Float16* __restrict__ whh,  // [1024][256] row-major f16
    const float* __restrict__ xw, long xw_seq_stride, long xw_t_stride, int T,
    float* __restrict__ h_out,   // [B*T][256] or nullptr
    float* __restrict__ c_out) { // [B][256] or nullptr
  __shared__ __align__(16) _Float16 ah[H_];
  __shared__ __align__(16) _Float16 wo[H_][260];
  const int t_ = threadIdx.x;
  const int p = t_ >> 1;
  const int hf = t_ & 1;
  const int b = blockIdx.x;

  v8h wv[3][16];
#pragma unroll
  for (int r = 0; r < 3; ++r) {
    const v8h* src = (const v8h*)(whh + ((size_t)(H_ * r + p)) * H_ + hf * 128);
#pragma unroll
    for (int q = 0; q < 16; ++q) wv[r][q] = src[q];
  }
  {
    const v4h* src = (const v4h*)(whh + ((size_t)(H_ * 3 + p)) * H_ + hf * 128);
    v4h* dst = (v4h*)&wo[p][hf * 128];
#pragma unroll
    for (int q = 0; q < 32; ++q) dst[q] = src[q];
  }
  if (t_ < H_) ah[t_] = (_Float16)0.f;
  float c = 0.f;
  __syncthreads();

  for (int t = 0; t < T; ++t) {
    const float* xwp = xw + (size_t)b * xw_seq_stride + (size_t)t * xw_t_stride;
    float x0 = xwp[p], x1 = xwp[H_ + p], x2 = xwp[2 * H_ + p], x3 = xwp[3 * H_ + p];
    float a0 = 0.f, a1 = 0.f, a2 = 0.f, a3 = 0.f;
    const v8h* A8 = ((const v8h*)ah) + hf * 16;
    const v4h* O4 = (const v4h*)&wo[p][hf * 128];
#pragma unroll
    for (int q = 0; q < 16; ++q) {
      v8h av = A8[q];
      v8h w0v = wv[0][q], w1v = wv[1][q], w2v = wv[2][q];
      v4h o0 = O4[2 * q], o1 = O4[2 * q + 1];
#pragma unroll
      for (int e = 0; e < 4; ++e) {
        v2h ap = ext8(av, e);
        a0 = fdot2f(ext8(w0v, e), ap, a0);
        a1 = fdot2f(ext8(w1v, e), ap, a1);
        a2 = fdot2f(ext8(w2v, e), ap, a2);
        v2h op = (e < 2) ? ext4(o0, e) : ext4(o1, e - 2);
        a3 = fdot2f(op, ap, a3);
      }
    }
    a0 += __shfl_xor(a0, 1);
    a1 += __shfl_xor(a1, 1);
    a2 += __shfl_xor(a2, 1);
    a3 += __shfl_xor(a3, 1);
    float gi = sigm(a0 + x0);
    float gf = sigm(a1 + x1);
    float gg = tanh_f(a2 + x2);
    float go = sigm(a3 + x3);
    c = gf * c + gi * gg;
    float h = go * tanh_f(c);
    __syncthreads();
    if (hf == 0) {
      ah[p] = (_Float16)h;
      if (h_out) h_out[((size_t)b * T + t) * H_ + p] = h;
    }
    __syncthreads();
  }
  if (c_out && hf == 0) c_out[(size_t)b * H_ + p] = c;
}

// ---------------------------------------------------------------------------
extern "C" void kernel_launch(void* const* d_in, const int* in_sizes, int n_in,
                              void* d_out, int out_size, void* d_ws, size_t ws_size,
                              hipStream_t stream) {
  const float* inp    = (const float*)d_in[0];
  const float* oe_wih = (const float*)d_in[1];
  const float* oe_whh = (const float*)d_in[2];
  const float* oe_bih = (const float*)d_in[3];
  const float* oe_bhh = (const float*)d_in[4];
  const float* ie_wih = (const float*)d_in[5];
  const float* ie_whh = (const float*)d_in[6];
  const float* ie_bih = (const float*)d_in[7];
  const float* ie_bhh = (const float*)d_in[8];
  const float* id_wih = (const float*)d_in[9];
  const float* id_whh = (const float*)d_in[10];
  const float* id_bih = (const float*)d_in[11];
  const float* id_bhh = (const float*)d_in[12];
  const float* od_wih = (const float*)d_in[13];
  const float* od_whh = (const float*)d_in[14];
  const float* od_bih = (const float*)d_in[15];
  const float* od_bhh = (const float*)d_in[16];

  char* ws = (char*)d_ws;
  _Float16* xT     = (_Float16*)(ws + 0);         // 76800*128 f16 = 19,660,800
  v8h* wpack_oe    = (v8h*)(ws + 19660800);       // 12*64*64*16  =    786,432
  float* cst       = (float*)(ws + 20447232);     // 3200*256*4   =  3,276,800
  v2h* wt2_ie      = (v2h*)(ws + 23724032);       // 128*1024*4   =    524,288
  float* xw_ie     = (float*)(ws + 24248320);     // 3200*1024*4  = 13,107,200
  _Float16* whh_ie = (_Float16*)(ws + 37355520);  // 262144 f16   =    524,288
  float* bott      = (float*)(ws + 37879808);     // 32*256*4     =     32,768
  v2h* wt2_id      = (v2h*)(ws + 37912576);       //              =    524,288
  float* xw_id     = (float*)(ws + 38436864);     // 32*1024*4    =    131,072
  _Float16* whh_id = (_Float16*)(ws + 38567936);  //              =    524,288
  float* dec       = (float*)(ws + 39092224);     // 3200*256*4   =  3,276,800
  v2h* wt2_odih    = (v2h*)(ws + 42369024);       // 128*512*4    =    262,144
  float* xw_od     = (float*)(ws + 42631168);     // 3200*512*4   =  6,553,600
  v8h* wpack_od    = (v8h*)(ws + 49184768);       // 4*32*64*16   =    131,072
  float* rec       = (float*)(ws + 49315840);     // 76800*128*4  = 39,321,600  (end 88.6 MB)

  // --- weight prep (fused: one launch instead of seven) ---
  k_prep<<<dim3(3552), dim3(256), 0, stream>>>(
      wpack_oe, wpack_od, wt2_ie, wt2_id, wt2_odih, whh_ie, whh_id,
      oe_wih, oe_whh, ie_wih, ie_whh, id_wih, id_whh, od_wih, od_whh);

  // --- pipeline ---
  k_tin<<<dim3(75, 4, 32), dim3(32, 8), 0, stream>>>(inp, xT);
  k_outer_enc_mfma<<<dim3(100), dim3(512), 0, stream>>>(wpack_oe, xT, oe_bih, oe_bhh, cst);
  k_proj<4><<<dim3(200), dim3(256), 0, stream>>>(cst, wt2_ie, ie_bih, ie_bhh, xw_ie);
  k_inner<<<dim3(32), dim3(512), 0, stream>>>(whh_ie, xw_ie, (long)S_ * 1024, 1024, S_, nullptr, bott);
  k_proj<4><<<dim3(2), dim3(256), 0, stream>>>(bott, wt2_id, id_bih, id_bhh, xw_id);
  k_inner<<<dim3(32), dim3(512), 0, stream>>>(whh_id, xw_id, 1024, 0, S_, dec, nullptr);
  k_proj<2><<<dim3(200), dim3(256), 0, stream>>>(dec, wt2_odih, od_bih, od_bhh, xw_od);
  k_outer_dec_mfma<<<dim3(100), dim3(1024), 0, stream>>>(wpack_od, xw_od, rec);
  k_tout<<<dim3(75, 4, 32), dim3(32, 8), 0, stream>>>(rec, (float*)d_out);

  (void)in_sizes; (void)n_in; (void)out_size; (void)ws_size;
}